// Round 6
// baseline (487.510 us; speedup 1.0000x reference)
//
#include <hip/hip_runtime.h>
#include <cstdint>

#define N 8192
#define NT 128     // 64-col chunks per row (N/64)
#define NGRP 64    // scan groups of 128 rows
#define NWV 7      // waves in the single scan block
typedef unsigned long long u64;
typedef unsigned int u32;

typedef __attribute__((address_space(1))) const void gas_void;
typedef __attribute__((address_space(3))) void las_void;

__device__ inline u64 readlane64(u64 v, int lane) {
  u32 lo = (u32)__builtin_amdgcn_readlane((int)(u32)v, lane);
  u32 hi = (u32)__builtin_amdgcn_readlane((int)(u32)(v >> 32), lane);
  return ((u64)hi << 32) | lo;
}

// ---------------------------------------------------------------------------
// K1: sort keys (descending score, stable ascending index) + init aux
// ---------------------------------------------------------------------------
__global__ __launch_bounds__(256) void k_init(const float* __restrict__ scores,
                                              u64* __restrict__ keys,
                                              int* __restrict__ rank,
                                              int* __restrict__ cnt,
                                              float* __restrict__ prob,
                                              unsigned* __restrict__ y2m,
                                              int* __restrict__ first) {
  int i = blockIdx.x * 256 + threadIdx.x;
  if (i >= N) return;
  float sc = scores[i];
  keys[i] = ((u64)__float_as_uint(sc) << 32) | (unsigned)(0xFFFFFFFFu - (unsigned)i);
  rank[i] = 0;
  cnt[i] = 0;
  prob[i] = 0.0f;
  y2m[i] = 0u;
  first[i] = N;
}

// ---------------------------------------------------------------------------
// K2: rank by counting (rank[i] = #{j : key[j] > key[i]}) -> stable descending
// ---------------------------------------------------------------------------
__global__ __launch_bounds__(256) void k_rank(const u64* __restrict__ keys,
                                              int* __restrict__ rank) {
  __shared__ u64 tile[1024];
  int e = blockIdx.x * 256 + threadIdx.x;
  int j0 = blockIdx.y * 1024;
  for (int t = threadIdx.x; t < 1024; t += 256) tile[t] = keys[j0 + t];
  __syncthreads();
  u64 ke = keys[e];
  int c = 0;
#pragma unroll 8
  for (int k = 0; k < 1024; ++k) c += (tile[k] > ke) ? 1 : 0;
  atomicAdd(&rank[e], c);
}

// ---------------------------------------------------------------------------
// K3: scatter into sorted SoA (clipped coords, score, area)
// ---------------------------------------------------------------------------
__global__ __launch_bounds__(256) void k_scatter(const float* __restrict__ boxes,
                                                 const float* __restrict__ scores,
                                                 const int* __restrict__ rank,
                                                 float* __restrict__ bx1s, float* __restrict__ by1s,
                                                 float* __restrict__ bx2s, float* __restrict__ by2s,
                                                 float* __restrict__ ss, float* __restrict__ areas) {
#pragma clang fp contract(off)
  int i = blockIdx.x * 256 + threadIdx.x;
  if (i >= N) return;
  int r = rank[i];
  float x1 = fminf(fmaxf(boxes[i * 4 + 0], 0.0f), 1920.0f);
  float y1 = fminf(fmaxf(boxes[i * 4 + 1], 0.0f), 1080.0f);
  float x2 = fminf(fmaxf(boxes[i * 4 + 2], 0.0f), 1920.0f);
  float y2 = fminf(fmaxf(boxes[i * 4 + 3], 0.0f), 1080.0f);
  bx1s[r] = x1; by1s[r] = y1; bx2s[r] = x2; by2s[r] = y2;
  ss[r] = scores[i];
  areas[r] = (x2 - x1 + 1.0f) * (y2 - y1 + 1.0f);
}

// ---------------------------------------------------------------------------
// K4: adjacency, TILED layout: mtile[(gy*128+gx)*64 + lane] = row (64gy+lane)'s
// bits over cols [64gx, 64gx+64). fp contract OFF, exact IEEE divide -> the
// iou>0.5 compare matches numpy bit-for-bit. Matrix float-exact symmetric
// (k_scan/k_cluster rely on column j == row j).
// ---------------------------------------------------------------------------
__global__ __launch_bounds__(64) void k_adj(const float* __restrict__ bx1s, const float* __restrict__ by1s,
                                            const float* __restrict__ bx2s, const float* __restrict__ by2s,
                                            const float* __restrict__ areas,
                                            u64* __restrict__ mtile) {
#pragma clang fp contract(off)
  __shared__ float jx1[64], jy1[64], jx2[64], jy2[64], ja[64];
  int l = threadIdx.x;
  int j = blockIdx.x * 64 + l;
  jx1[l] = bx1s[j]; jy1[l] = by1s[j]; jx2[l] = bx2s[j]; jy2[l] = by2s[j]; ja[l] = areas[j];
  __syncthreads();
  int i = blockIdx.y * 64 + l;
  float x1 = bx1s[i], y1 = by1s[i], x2 = bx2s[i], y2 = by2s[i], ai = areas[i];
  u64 bits = 0;
#pragma unroll 4
  for (int jj = 0; jj < 64; ++jj) {
    float ix1 = fmaxf(x1, jx1[jj]);
    float iy1 = fmaxf(y1, jy1[jj]);
    float ix2 = fminf(x2, jx2[jj]);
    float iy2 = fminf(y2, jy2[jj]);
    float iw = fmaxf(ix2 - ix1 + 1.0f, 0.0f);
    float ih = fmaxf(iy2 - iy1 + 1.0f, 0.0f);
    float inter = iw * ih;
    float uni = (ai + ja[jj]) - inter;
    float iou = inter / uni;
    bits |= ((u64)(iou > 0.5f)) << jj;
  }
  mtile[((size_t)blockIdx.y * NT + blockIdx.x) * 64 + l] = bits;
}

// ---------------------------------------------------------------------------
// K5: head discovery — single block, 7 waves, chain through LDS.
// R3/R4/R5 all plateaued at ~280us: the fabric-atomic publish->detect hop is
// ~4.4us and 63 hops are structural. Here the hop is an LDS release/acquire
// (~100cy). Wave w owns groups g ≡ w (mod 7); consecutive groups are always
// different co-resident waves -> no deadlock. mtile strips are static data,
// fully decoupled from the chain: streamed via LDS-DMA windows of 8 chunks,
// consumed pair-by-pair with exact manual vmcnt (only DMAs outstanding).
// Output: pub[k] = head bits of chunk k (plain words, read by k_cluster).
// ---------------------------------------------------------------------------
__global__ __launch_bounds__(64 * NWV, 1) void k_scan(const u64* __restrict__ mtile,
                                                      u64* __restrict__ pub) {
  __shared__ u64 win[NWV][2][512];   // 8-chunk window per rowtile per wave
  __shared__ u64 hlds[NT];           // published head words
  __shared__ int prog;               // chunks published (monotonic)
  const int w = threadIdx.x >> 6;
  const int r = threadIdx.x & 63;
  if (threadIdx.x == 0)
    __hip_atomic_store(&prog, 0, __ATOMIC_RELAXED, __HIP_MEMORY_SCOPE_WORKGROUP);
  __syncthreads();
  int seen = 0;

  for (int g = w; g < NGRP; g += NWV) {
    const int ra = 2 * g, rb = 2 * g + 1, kend = 2 * g;
    u64 dAA = mtile[((size_t)ra * NT + ra) * 64 + r];
    u64 dAB = mtile[((size_t)ra * NT + rb) * 64 + r];
    u64 dBB = mtile[((size_t)rb * NT + rb) * 64 + r];
    // drain plain vmem so manual vmcnt counts below see ONLY our DMAs
    asm volatile("s_waitcnt vmcnt(0)" ::: "memory");
    u64 acc0 = 0, acc1 = 0;

    for (int base = 0; base < kend; base += 8) {
      const u64* gA = mtile + ((size_t)ra * NT + base) * 64;
      const u64* gB = mtile + ((size_t)rb * NT + base) * 64;
      // issue 8 DMAs: pair q covers chunks {base+2q, base+2q+1} for A and B
#pragma unroll
      for (int q = 0; q < 4; ++q) {
        __builtin_amdgcn_global_load_lds((gas_void*)(gA + q * 128 + 2 * r),
                                         (las_void*)(&win[w][0][q * 128]), 16, 0, 0);
        __builtin_amdgcn_global_load_lds((gas_void*)(gB + q * 128 + 2 * r),
                                         (las_void*)(&win[w][1][q * 128]), 16, 0, 0);
      }
      // consume pair q once its 2 DMAs retired: outstanding <= 6-2q.
      // (FIFO vmcnt; leftovers from skipped pairs only make waits cover more.)
#define CONSUME_PAIR(Q, VM)                                                        \
      {                                                                            \
        asm volatile("s_waitcnt vmcnt(" #VM ")" ::: "memory");                     \
        _Pragma("unroll")                                                          \
        for (int t = 2 * Q; t < 2 * Q + 2; ++t) {                                  \
          int k = base + t;                                                        \
          if (k < kend) {                                                          \
            if (seen <= k) {                                                       \
              while ((seen = __hip_atomic_load(&prog, __ATOMIC_ACQUIRE,            \
                                               __HIP_MEMORY_SCOPE_WORKGROUP)) <= k)\
                __builtin_amdgcn_s_sleep(1);                                       \
            }                                                                      \
            u64 h = hlds[k];                                                       \
            acc0 |= __ballot((win[w][0][t * 64 + r] & h) != 0ull);                 \
            acc1 |= __ballot((win[w][1][t * 64 + r] & h) != 0ull);                 \
          }                                                                        \
        }                                                                          \
      }
      CONSUME_PAIR(0, 6)
      CONSUME_PAIR(1, 4)
      CONSUME_PAIR(2, 2)
      CONSUME_PAIR(3, 0)
#undef CONSUME_PAIR
    }

    // our turn: prog == kend (implied by last consume; explicit for g's first)
    if (seen < kend) {
      while ((seen = __hip_atomic_load(&prog, __ATOMIC_ACQUIRE,
                                       __HIP_MEMORY_SCOPE_WORKGROUP)) < kend)
        __builtin_amdgcn_s_sleep(1);
    }
    // in-group greedy resolve (uniform; self-bit adj[i][i]=1 clears i)
    u64 todo0 = ~acc0, todo1 = ~acc1, hm0 = 0, hm1 = 0;
    while (todo0) {
      int i = __builtin_ctzll(todo0);
      hm0 |= 1ull << i;
      todo0 &= ~readlane64(dAA, i);
      todo1 &= ~readlane64(dAB, i);
    }
    while (todo1) {
      int i = __builtin_ctzll(todo1);
      hm1 |= 1ull << i;
      todo1 &= ~readlane64(dBB, i);
    }
    if (r == 0) {
      hlds[ra] = hm0; hlds[rb] = hm1;   // ds_write before release
      pub[ra] = hm0;  pub[rb] = hm1;    // for k_cluster (kernel-boundary sync)
      __hip_atomic_store(&prog, kend + 2, __ATOMIC_RELEASE,
                         __HIP_MEMORY_SCOPE_WORKGROUP);
    }
  }
}

// ---------------------------------------------------------------------------
// K6: parallel cluster assignment + segment atomics. Block per 64-row group;
// wave w scans col-chunks [32w,32w+32) coalesced; cluster[j] = first head
// adjacent to j (symmetry: row j == column j). Every j hits (itself if head).
// ---------------------------------------------------------------------------
__global__ __launch_bounds__(256) void k_cluster(const u64* __restrict__ mtile,
                                                 const u64* __restrict__ pub,
                                                 const float* __restrict__ ss,
                                                 const float* __restrict__ by2s,
                                                 int* __restrict__ cluster,
                                                 int* __restrict__ cnt,
                                                 float* __restrict__ prob,
                                                 unsigned* __restrict__ y2m) {
  __shared__ u64 hlds[NT];
  __shared__ int red[4][64];
  int gy = blockIdx.x;
  if (threadIdx.x < NT) hlds[threadIdx.x] = pub[threadIdx.x];
  __syncthreads();
  int w = threadIdx.x >> 6, r = threadIdx.x & 63;
  int best = 0x7fffffff;
  for (int kk = 0; kk < 32; ++kk) {
    int k = 32 * w + kk;
    u64 v = mtile[((size_t)gy * NT + k) * 64 + r] & hlds[k];
    if (v && best == 0x7fffffff) best = k * 64 + __builtin_ctzll(v);
  }
  red[w][r] = best;
  __syncthreads();
  if (w == 0) {
    int b = min(min(red[0][r], red[1][r]), min(red[2][r], red[3][r]));
    int j = gy * 64 + r;
    cluster[j] = b;
    atomicAdd(&cnt[b], 1);
    atomicAdd(&prob[b], ss[j]);
    atomicMax(&y2m[b], __float_as_uint(by2s[j]));
  }
}

// ---------------------------------------------------------------------------
// K7: first index achieving the cluster max y2
// ---------------------------------------------------------------------------
__global__ __launch_bounds__(256) void k_first(const int* __restrict__ cluster,
                                               const float* __restrict__ by2s,
                                               const unsigned* __restrict__ y2m,
                                               int* __restrict__ first) {
  int j = blockIdx.x * 256 + threadIdx.x;
  if (j >= N) return;
  int c = cluster[j];
  if (by2s[j] >= __uint_as_float(y2m[c])) atomicMin(&first[c], j);
}

// ---------------------------------------------------------------------------
// K8: outputs. out[j][0..4] then keep[j] appended (floats 0/1).
// ---------------------------------------------------------------------------
__global__ __launch_bounds__(256) void k_out(const int* __restrict__ cluster,
                                             const float* __restrict__ bx1s, const float* __restrict__ by1s,
                                             const float* __restrict__ bx2s, const float* __restrict__ by2s,
                                             const int* __restrict__ cnt,
                                             const float* __restrict__ prob,
                                             const int* __restrict__ first,
                                             const int* __restrict__ num_models,
                                             float* __restrict__ out) {
  int j = blockIdx.x * 256 + threadIdx.x;
  if (j >= N) return;
  int c = cluster[j];
  int nm = num_models[0];
  bool valid = (float)cnt[c] >= (float)nm / 3.0f;
  bool pick = (first[c] == j);
  bool keep = pick && valid;
  float o0 = 0.f, o1 = 0.f, o2 = 0.f, o3 = 0.f, o4 = 0.f;
  if (keep) {
    o0 = bx1s[j]; o1 = by1s[j]; o2 = bx2s[j]; o3 = by2s[j];
    o4 = prob[c] / (float)nm;
  }
  out[j * 5 + 0] = o0;
  out[j * 5 + 1] = o1;
  out[j * 5 + 2] = o2;
  out[j * 5 + 3] = o3;
  out[j * 5 + 4] = o4;
  out[N * 5 + j] = keep ? 1.0f : 0.0f;
}

// ---------------------------------------------------------------------------
extern "C" void kernel_launch(void* const* d_in, const int* in_sizes, int n_in,
                              void* d_out, int out_size, void* d_ws, size_t ws_size,
                              hipStream_t stream) {
  const float* boxes = (const float*)d_in[0];
  const float* scores = (const float*)d_in[1];
  const int* num_models = (const int*)d_in[2];
  float* out = (float*)d_out;

  char* p = (char*)d_ws;
  auto take = [&](size_t bytes) {
    char* r = p;
    p += (bytes + 255) & ~(size_t)255;
    return r;
  };
  u64* keys   = (u64*)take((size_t)N * 8);
  int* rank   = (int*)take((size_t)N * 4);
  float* bx1s = (float*)take((size_t)N * 4);
  float* by1s = (float*)take((size_t)N * 4);
  float* bx2s = (float*)take((size_t)N * 4);
  float* by2s = (float*)take((size_t)N * 4);
  float* ss   = (float*)take((size_t)N * 4);
  float* areas= (float*)take((size_t)N * 4);
  int* cluster= (int*)take((size_t)N * 4);
  int* cnt    = (int*)take((size_t)N * 4);
  float* prob = (float*)take((size_t)N * 4);
  unsigned* y2m = (unsigned*)take((size_t)N * 4);
  int* first  = (int*)take((size_t)N * 4);
  u64* pub    = (u64*)take((size_t)NT * 8);           // 128 head words
  u64* mtile  = (u64*)take((size_t)NT * NT * 64 * 8); // 8 MiB tiled adjacency

  k_init<<<N / 256, 256, 0, stream>>>(scores, keys, rank, cnt, prob, y2m, first);
  k_rank<<<dim3(N / 256, 8), 256, 0, stream>>>(keys, rank);
  k_scatter<<<N / 256, 256, 0, stream>>>(boxes, scores, rank, bx1s, by1s, bx2s, by2s, ss, areas);
  k_adj<<<dim3(NT, NT), 64, 0, stream>>>(bx1s, by1s, bx2s, by2s, areas, mtile);
  k_scan<<<1, 64 * NWV, 0, stream>>>(mtile, pub);
  k_cluster<<<N / 64, 256, 0, stream>>>(mtile, pub, ss, by2s, cluster, cnt, prob, y2m);
  k_first<<<N / 256, 256, 0, stream>>>(cluster, by2s, y2m, first);
  k_out<<<N / 256, 256, 0, stream>>>(cluster, bx1s, by1s, bx2s, by2s, cnt, prob, first, num_models, out);
}

// Round 7
// 184.807 us; speedup vs baseline: 2.6379x; 2.6379x over previous
//
#include <hip/hip_runtime.h>
#include <cstdint>

#define N 8192
#define NT 128     // 64-col chunks per row (N/64)
#define NROUNDS 8  // parallel classification rounds (correctness-independent)
typedef unsigned long long u64;
typedef unsigned int u32;

// ---------------------------------------------------------------------------
// K1: sort keys (descending score, stable ascending index) + init aux + D,S=0
// ---------------------------------------------------------------------------
__global__ __launch_bounds__(256) void k_init(const float* __restrict__ scores,
                                              u64* __restrict__ keys,
                                              int* __restrict__ rank,
                                              int* __restrict__ cnt,
                                              float* __restrict__ prob,
                                              unsigned* __restrict__ y2m,
                                              int* __restrict__ first,
                                              u64* __restrict__ D,
                                              u64* __restrict__ S) {
  int i = blockIdx.x * 256 + threadIdx.x;
  if (i >= N) return;
  float sc = scores[i];
  keys[i] = ((u64)__float_as_uint(sc) << 32) | (unsigned)(0xFFFFFFFFu - (unsigned)i);
  rank[i] = 0;
  cnt[i] = 0;
  prob[i] = 0.0f;
  y2m[i] = 0u;
  first[i] = N;
  if (i < NT) { D[i] = 0ull; S[i] = 0ull; }
}

// ---------------------------------------------------------------------------
// K2: rank by counting (rank[i] = #{j : key[j] > key[i]}) -> stable descending
// ---------------------------------------------------------------------------
__global__ __launch_bounds__(256) void k_rank(const u64* __restrict__ keys,
                                              int* __restrict__ rank) {
  __shared__ u64 tile[1024];
  int e = blockIdx.x * 256 + threadIdx.x;
  int j0 = blockIdx.y * 1024;
  for (int t = threadIdx.x; t < 1024; t += 256) tile[t] = keys[j0 + t];
  __syncthreads();
  u64 ke = keys[e];
  int c = 0;
#pragma unroll 8
  for (int k = 0; k < 1024; ++k) c += (tile[k] > ke) ? 1 : 0;
  atomicAdd(&rank[e], c);
}

// ---------------------------------------------------------------------------
// K3: scatter into sorted SoA (clipped coords, score, area)
// ---------------------------------------------------------------------------
__global__ __launch_bounds__(256) void k_scatter(const float* __restrict__ boxes,
                                                 const float* __restrict__ scores,
                                                 const int* __restrict__ rank,
                                                 float* __restrict__ bx1s, float* __restrict__ by1s,
                                                 float* __restrict__ bx2s, float* __restrict__ by2s,
                                                 float* __restrict__ ss, float* __restrict__ areas) {
#pragma clang fp contract(off)
  int i = blockIdx.x * 256 + threadIdx.x;
  if (i >= N) return;
  int r = rank[i];
  float x1 = fminf(fmaxf(boxes[i * 4 + 0], 0.0f), 1920.0f);
  float y1 = fminf(fmaxf(boxes[i * 4 + 1], 0.0f), 1080.0f);
  float x2 = fminf(fmaxf(boxes[i * 4 + 2], 0.0f), 1920.0f);
  float y2 = fminf(fmaxf(boxes[i * 4 + 3], 0.0f), 1080.0f);
  bx1s[r] = x1; by1s[r] = y1; bx2s[r] = x2; by2s[r] = y2;
  ss[r] = scores[i];
  areas[r] = (x2 - x1 + 1.0f) * (y2 - y1 + 1.0f);
}

// ---------------------------------------------------------------------------
// K4: adjacency, SYMMETRIC: one block per (gy>=gx) tile pair. Computes the
// (gy,gx) 64x64 tile directly (exact IEEE div, fp contract off -> matches
// numpy bit-for-bit; matrix float-exact symmetric), stores it, and mirrors
// the transpose to (gx,gy) via 64 ballots (6x cheaper than recompute; halves
// the divide work). Both layouts written: mtile (tiled; k_round/k_cluster)
// and mrow (row-major; k_fix coalesced row fetch).
// ---------------------------------------------------------------------------
__global__ __launch_bounds__(64) void k_adj(const float* __restrict__ bx1s, const float* __restrict__ by1s,
                                            const float* __restrict__ bx2s, const float* __restrict__ by2s,
                                            const float* __restrict__ areas,
                                            u64* __restrict__ mtile,
                                            u64* __restrict__ mrow) {
#pragma clang fp contract(off)
  __shared__ float jx1[64], jy1[64], jx2[64], jy2[64], ja[64];
  int p = blockIdx.x;
  int gy = (int)((sqrtf(8.0f * (float)p + 1.0f) - 1.0f) * 0.5f);
  while ((gy + 1) * (gy + 2) / 2 <= p) ++gy;
  while (gy * (gy + 1) / 2 > p) --gy;
  int gx = p - gy * (gy + 1) / 2;

  int l = threadIdx.x;
  int j = gx * 64 + l;
  jx1[l] = bx1s[j]; jy1[l] = by1s[j]; jx2[l] = bx2s[j]; jy2[l] = by2s[j]; ja[l] = areas[j];
  __syncthreads();
  int i = gy * 64 + l;
  float x1 = bx1s[i], y1 = by1s[i], x2 = bx2s[i], y2 = by2s[i], ai = areas[i];
  u64 bits = 0;
#pragma unroll 4
  for (int jj = 0; jj < 64; ++jj) {
    float ix1 = fmaxf(x1, jx1[jj]);
    float iy1 = fmaxf(y1, jy1[jj]);
    float ix2 = fminf(x2, jx2[jj]);
    float iy2 = fminf(y2, jy2[jj]);
    float iw = fmaxf(ix2 - ix1 + 1.0f, 0.0f);
    float ih = fmaxf(iy2 - iy1 + 1.0f, 0.0f);
    float inter = iw * ih;
    float uni = (ai + ja[jj]) - inter;
    float iou = inter / uni;
    bits |= ((u64)(iou > 0.5f)) << jj;
  }
  mtile[((size_t)gy * NT + gx) * 64 + l] = bits;
  mrow[(size_t)i * NT + gx] = bits;
  if (gx != gy) {
    // transpose: T'[c] (word for row gx*64+c over cols gy-range) has bit
    // jj' = T[jj'][c] = ballot bit jj' of ((bits>>c)&1)
    u64 tb = 0;
#pragma unroll 8
    for (int c = 0; c < 64; ++c) {
      u64 wb = __ballot((bits >> c) & 1ull);
      tb = (l == c) ? wb : tb;
    }
    mtile[((size_t)gx * NT + gy) * 64 + l] = tb;
    mrow[(size_t)(gx * 64 + l) * NT + gy] = tb;
  }
}

// ---------------------------------------------------------------------------
// K5 (x NROUNDS): monotone parallel classification round.
// D = definitely-head bitmap, S = definitely-suppressed bitmap (128 u64 each).
// Sound rules (any stale view only delays, never corrupts):
//   suppressed: some earlier neighbor in D
//   head:       ALL earlier neighbors in S
// Block per 64-row tile gy; 4 waves split the chunk range; lane r = row.
// Classified rows skip all loads -> later rounds shrink. Publishes via
// atomicOr. Correctness does NOT depend on convergence (k_fix is exact).
// ---------------------------------------------------------------------------
__global__ __launch_bounds__(256) void k_round(const u64* __restrict__ mtile,
                                               u64* __restrict__ D,
                                               u64* __restrict__ S) {
  __shared__ u64 Dl[NT], Sl[NT];
  __shared__ u64 bw[2][4];
  int gy = blockIdx.x;
  int t = threadIdx.x;
  if (t < NT) Dl[t] = D[t];
  else Sl[t - NT] = S[t - NT];
  __syncthreads();
  u64 classified = Dl[gy] | Sl[gy];
  if (classified == ~0ull) return;   // whole tile done (uniform)
  int w = t >> 6, r = t & 63;
  bool unk = !((classified >> r) & 1ull);
  u64 anyD = 0, anyU = 0;
  if (unk) {
    int k0 = 32 * w, k1 = min(k0 + 32, gy + 1);
    for (int k = k0; k < k1; ++k) {
      u64 m = mtile[((size_t)gy * NT + k) * 64 + r];
      if (k == gy) m &= (1ull << r) - 1ull;   // strictly earlier within own tile
      anyD |= (m & Dl[k]);
      anyU |= (m & ~Sl[k]);
    }
  }
  u64 bD = __ballot(anyD != 0ull), bU = __ballot(anyU != 0ull);
  if (r == 0) { bw[0][w] = bD; bw[1][w] = bU; }
  __syncthreads();
  if (t == 0) {
    u64 rD = bw[0][0] | bw[0][1] | bw[0][2] | bw[0][3];
    u64 rU = bw[1][0] | bw[1][1] | bw[1][2] | bw[1][3];
    u64 unkb = ~classified;
    u64 newS = unkb & rD;
    u64 newD = unkb & ~rD & ~rU;
    if (newS) atomicOr(&S[gy], newS);
    if (newD) atomicOr(&D[gy], newD);
  }
}

// ---------------------------------------------------------------------------
// K6: exact serial cleanup, ONE wave. Processes unknown rows ascending.
// Invariant: when row j is tested, D contains ALL true heads < j (rounds'
// heads are correct; unknown heads < j were found earlier in this loop).
// So (row_j & D & below) == 0  <=>  j is a head. Exact for ANY round state.
// Rows fetched coalesced (1 KB) from mrow via 8-deep register ring.
// D held in registers (lane l: words 2l,2l+1); final D written back.
// ---------------------------------------------------------------------------
__global__ __launch_bounds__(64, 1) void k_fix(const u64* __restrict__ mrow,
                                               u64* __restrict__ D,
                                               const u64* __restrict__ S) {
  __shared__ int ulist[N];
  int l = threadIdx.x;
  u64 D0 = D[2 * l], D1 = D[2 * l + 1];
  u64 S0 = S[2 * l], S1 = S[2 * l + 1];
  u64 u0 = ~(D0 | S0), u1 = ~(D1 | S1);
  int cnt = __popcll(u0) + __popcll(u1);
  int pre = cnt;
  for (int d = 1; d < 64; d <<= 1) {
    int v = __shfl_up(pre, d);
    if (l >= d) pre += v;
  }
  int M = __shfl(pre, 63);
  int off = pre - cnt;
  {
    u64 v = u0; int o = off;
    while (v) { int b = __builtin_ctzll(v); v &= v - 1; ulist[o++] = l * 128 + b; }
    v = u1;
    while (v) { int b = __builtin_ctzll(v); v &= v - 1; ulist[o++] = l * 128 + 64 + b; }
  }
  __syncthreads();
  if (M > 0) {
    ulong2 ring[8];
    int pj[8];
#pragma unroll
    for (int q = 0; q < 8; ++q) {
      int j = ulist[q < M ? q : M - 1];
      pj[q] = j;
      ring[q] = *(const ulong2*)&mrow[(size_t)j * NT + 2 * l];
    }
    for (int m = 0; m < M; ++m) {
      int slot = m & 7;
      int j = pj[slot];
      ulong2 rv = ring[slot];
      int jt = j >> 6;
      u64 bm = (1ull << (j & 63)) - 1ull;
      u64 m0 = (2 * l < jt) ? ~0ull : ((2 * l == jt) ? bm : 0ull);
      u64 m1 = (2 * l + 1 < jt) ? ~0ull : ((2 * l + 1 == jt) ? bm : 0ull);
      bool hit = ((rv.x & D0 & m0) | (rv.y & D1 & m1)) != 0ull;
      if (__ballot(hit) == 0ull) {          // no earlier head adjacent -> head
        if (l == (jt >> 1)) {
          if (jt & 1) D1 |= 1ull << (j & 63);
          else        D0 |= 1ull << (j & 63);
        }
      }
      int nm = m + 8;
      int j2 = ulist[nm < M ? nm : M - 1];
      pj[slot] = j2;
      ring[slot] = *(const ulong2*)&mrow[(size_t)j2 * NT + 2 * l];
    }
  }
  D[2 * l] = D0;
  D[2 * l + 1] = D1;
}

// ---------------------------------------------------------------------------
// K7: parallel cluster assignment + segment atomics. cluster[j] = first head
// adjacent to j (symmetry: row j == column j). Every j hits (itself if head).
// ---------------------------------------------------------------------------
__global__ __launch_bounds__(256) void k_cluster(const u64* __restrict__ mtile,
                                                 const u64* __restrict__ D,
                                                 const float* __restrict__ ss,
                                                 const float* __restrict__ by2s,
                                                 int* __restrict__ cluster,
                                                 int* __restrict__ cnt,
                                                 float* __restrict__ prob,
                                                 unsigned* __restrict__ y2m) {
  __shared__ u64 hlds[NT];
  __shared__ int red[4][64];
  int gy = blockIdx.x;
  if (threadIdx.x < NT) hlds[threadIdx.x] = D[threadIdx.x];
  __syncthreads();
  int w = threadIdx.x >> 6, r = threadIdx.x & 63;
  int best = 0x7fffffff;
  for (int kk = 0; kk < 32; ++kk) {
    int k = 32 * w + kk;
    u64 v = mtile[((size_t)gy * NT + k) * 64 + r] & hlds[k];
    if (v && best == 0x7fffffff) best = k * 64 + __builtin_ctzll(v);
  }
  red[w][r] = best;
  __syncthreads();
  if (w == 0) {
    int b = min(min(red[0][r], red[1][r]), min(red[2][r], red[3][r]));
    int j = gy * 64 + r;
    cluster[j] = b;
    atomicAdd(&cnt[b], 1);
    atomicAdd(&prob[b], ss[j]);
    atomicMax(&y2m[b], __float_as_uint(by2s[j]));
  }
}

// ---------------------------------------------------------------------------
// K8: first index achieving the cluster max y2
// ---------------------------------------------------------------------------
__global__ __launch_bounds__(256) void k_first(const int* __restrict__ cluster,
                                               const float* __restrict__ by2s,
                                               const unsigned* __restrict__ y2m,
                                               int* __restrict__ first) {
  int j = blockIdx.x * 256 + threadIdx.x;
  if (j >= N) return;
  int c = cluster[j];
  if (by2s[j] >= __uint_as_float(y2m[c])) atomicMin(&first[c], j);
}

// ---------------------------------------------------------------------------
// K9: outputs. out[j][0..4] then keep[j] appended (floats 0/1).
// ---------------------------------------------------------------------------
__global__ __launch_bounds__(256) void k_out(const int* __restrict__ cluster,
                                             const float* __restrict__ bx1s, const float* __restrict__ by1s,
                                             const float* __restrict__ bx2s, const float* __restrict__ by2s,
                                             const int* __restrict__ cnt,
                                             const float* __restrict__ prob,
                                             const int* __restrict__ first,
                                             const int* __restrict__ num_models,
                                             float* __restrict__ out) {
  int j = blockIdx.x * 256 + threadIdx.x;
  if (j >= N) return;
  int c = cluster[j];
  int nm = num_models[0];
  bool valid = (float)cnt[c] >= (float)nm / 3.0f;
  bool pick = (first[c] == j);
  bool keep = pick && valid;
  float o0 = 0.f, o1 = 0.f, o2 = 0.f, o3 = 0.f, o4 = 0.f;
  if (keep) {
    o0 = bx1s[j]; o1 = by1s[j]; o2 = bx2s[j]; o3 = by2s[j];
    o4 = prob[c] / (float)nm;
  }
  out[j * 5 + 0] = o0;
  out[j * 5 + 1] = o1;
  out[j * 5 + 2] = o2;
  out[j * 5 + 3] = o3;
  out[j * 5 + 4] = o4;
  out[N * 5 + j] = keep ? 1.0f : 0.0f;
}

// ---------------------------------------------------------------------------
extern "C" void kernel_launch(void* const* d_in, const int* in_sizes, int n_in,
                              void* d_out, int out_size, void* d_ws, size_t ws_size,
                              hipStream_t stream) {
  const float* boxes = (const float*)d_in[0];
  const float* scores = (const float*)d_in[1];
  const int* num_models = (const int*)d_in[2];
  float* out = (float*)d_out;

  char* p = (char*)d_ws;
  auto take = [&](size_t bytes) {
    char* r = p;
    p += (bytes + 255) & ~(size_t)255;
    return r;
  };
  u64* keys   = (u64*)take((size_t)N * 8);
  int* rank   = (int*)take((size_t)N * 4);
  float* bx1s = (float*)take((size_t)N * 4);
  float* by1s = (float*)take((size_t)N * 4);
  float* bx2s = (float*)take((size_t)N * 4);
  float* by2s = (float*)take((size_t)N * 4);
  float* ss   = (float*)take((size_t)N * 4);
  float* areas= (float*)take((size_t)N * 4);
  int* cluster= (int*)take((size_t)N * 4);
  int* cnt    = (int*)take((size_t)N * 4);
  float* prob = (float*)take((size_t)N * 4);
  unsigned* y2m = (unsigned*)take((size_t)N * 4);
  int* first  = (int*)take((size_t)N * 4);
  u64* D      = (u64*)take((size_t)NT * 8);           // head bitmap
  u64* S      = (u64*)take((size_t)NT * 8);           // suppressed bitmap
  u64* mtile  = (u64*)take((size_t)NT * NT * 64 * 8); // 8 MiB tiled adjacency
  u64* mrow   = (u64*)take((size_t)N * NT * 8);       // 8 MiB row-major adjacency

  k_init<<<N / 256, 256, 0, stream>>>(scores, keys, rank, cnt, prob, y2m, first, D, S);
  k_rank<<<dim3(N / 256, 8), 256, 0, stream>>>(keys, rank);
  k_scatter<<<N / 256, 256, 0, stream>>>(boxes, scores, rank, bx1s, by1s, bx2s, by2s, ss, areas);
  k_adj<<<NT * (NT + 1) / 2, 64, 0, stream>>>(bx1s, by1s, bx2s, by2s, areas, mtile, mrow);
  for (int r = 0; r < NROUNDS; ++r)
    k_round<<<NT, 256, 0, stream>>>(mtile, D, S);
  k_fix<<<1, 64, 0, stream>>>(mrow, D, S);
  k_cluster<<<N / 64, 256, 0, stream>>>(mtile, D, ss, by2s, cluster, cnt, prob, y2m);
  k_first<<<N / 256, 256, 0, stream>>>(cluster, by2s, y2m, first);
  k_out<<<N / 256, 256, 0, stream>>>(cluster, bx1s, by1s, bx2s, by2s, cnt, prob, first, num_models, out);
}

// Round 8
// 178.884 us; speedup vs baseline: 2.7253x; 1.0331x over previous
//
#include <hip/hip_runtime.h>
#include <cstdint>

#define N 8192
#define NT 128     // 64-col chunks per row (N/64)
#define NROUNDS 4  // parallel classification rounds (correctness-independent)
typedef unsigned long long u64;
typedef unsigned int u32;

// ---------------------------------------------------------------------------
// K1: sort keys (descending score, stable ascending index) + init aux + D,S=0
// ---------------------------------------------------------------------------
__global__ __launch_bounds__(256) void k_init(const float* __restrict__ scores,
                                              u64* __restrict__ keys,
                                              int* __restrict__ rank,
                                              int* __restrict__ cnt,
                                              float* __restrict__ prob,
                                              unsigned* __restrict__ y2m,
                                              int* __restrict__ first,
                                              u64* __restrict__ D,
                                              u64* __restrict__ S) {
  int i = blockIdx.x * 256 + threadIdx.x;
  if (i >= N) return;
  float sc = scores[i];
  keys[i] = ((u64)__float_as_uint(sc) << 32) | (unsigned)(0xFFFFFFFFu - (unsigned)i);
  rank[i] = 0;
  cnt[i] = 0;
  prob[i] = 0.0f;
  y2m[i] = 0u;
  first[i] = N;
  if (i < NT) { D[i] = 0ull; S[i] = 0ull; }
}

// ---------------------------------------------------------------------------
// K2: rank by counting (rank[i] = #{j : key[j] > key[i]}) -> stable descending
// ---------------------------------------------------------------------------
__global__ __launch_bounds__(256) void k_rank(const u64* __restrict__ keys,
                                              int* __restrict__ rank) {
  __shared__ u64 tile[1024];
  int e = blockIdx.x * 256 + threadIdx.x;
  int j0 = blockIdx.y * 1024;
  for (int t = threadIdx.x; t < 1024; t += 256) tile[t] = keys[j0 + t];
  __syncthreads();
  u64 ke = keys[e];
  int c = 0;
#pragma unroll 8
  for (int k = 0; k < 1024; ++k) c += (tile[k] > ke) ? 1 : 0;
  atomicAdd(&rank[e], c);
}

// ---------------------------------------------------------------------------
// K3: scatter into sorted SoA (clipped coords, score, area)
// ---------------------------------------------------------------------------
__global__ __launch_bounds__(256) void k_scatter(const float* __restrict__ boxes,
                                                 const float* __restrict__ scores,
                                                 const int* __restrict__ rank,
                                                 float* __restrict__ bx1s, float* __restrict__ by1s,
                                                 float* __restrict__ bx2s, float* __restrict__ by2s,
                                                 float* __restrict__ ss, float* __restrict__ areas) {
#pragma clang fp contract(off)
  int i = blockIdx.x * 256 + threadIdx.x;
  if (i >= N) return;
  int r = rank[i];
  float x1 = fminf(fmaxf(boxes[i * 4 + 0], 0.0f), 1920.0f);
  float y1 = fminf(fmaxf(boxes[i * 4 + 1], 0.0f), 1080.0f);
  float x2 = fminf(fmaxf(boxes[i * 4 + 2], 0.0f), 1920.0f);
  float y2 = fminf(fmaxf(boxes[i * 4 + 3], 0.0f), 1080.0f);
  bx1s[r] = x1; by1s[r] = y1; bx2s[r] = x2; by2s[r] = y2;
  ss[r] = scores[i];
  areas[r] = (x2 - x1 + 1.0f) * (y2 - y1 + 1.0f);
}

// ---------------------------------------------------------------------------
// K4: adjacency, SYMMETRIC lower-triangle blocks + ballot transpose.
// R7 profile: VALUBusy 76%, 42us -> the exact IEEE v_div lowering (~15+ ops)
// dominated. Band trick: iou>0.5 <=> 2*inter>uni whenever |2*inter-uni| >
// 1e-6*uni (RN division error <= 3e-8 rel << 5e-7 band margin -> provably
// identical decision); only in-band lanes (expected ~1e2 of 33.8M) take the
// exact divide, guarded by a wave ballot so the div path is branched around.
// fp contract OFF everywhere; matrix float-exact symmetric.
// ---------------------------------------------------------------------------
__global__ __launch_bounds__(64) void k_adj(const float* __restrict__ bx1s, const float* __restrict__ by1s,
                                            const float* __restrict__ bx2s, const float* __restrict__ by2s,
                                            const float* __restrict__ areas,
                                            u64* __restrict__ mtile,
                                            u64* __restrict__ mrow) {
#pragma clang fp contract(off)
  __shared__ float jx1[64], jy1[64], jx2[64], jy2[64], ja[64];
  int p = blockIdx.x;
  int gy = (int)((sqrtf(8.0f * (float)p + 1.0f) - 1.0f) * 0.5f);
  while ((gy + 1) * (gy + 2) / 2 <= p) ++gy;
  while (gy * (gy + 1) / 2 > p) --gy;
  int gx = p - gy * (gy + 1) / 2;

  int l = threadIdx.x;
  int j = gx * 64 + l;
  jx1[l] = bx1s[j]; jy1[l] = by1s[j]; jx2[l] = bx2s[j]; jy2[l] = by2s[j]; ja[l] = areas[j];
  __syncthreads();
  int i = gy * 64 + l;
  float x1 = bx1s[i], y1 = by1s[i], x2 = bx2s[i], y2 = by2s[i], ai = areas[i];
  u64 bits = 0;
#pragma unroll 4
  for (int jj = 0; jj < 64; ++jj) {
    float ix1 = fmaxf(x1, jx1[jj]);
    float iy1 = fmaxf(y1, jy1[jj]);
    float ix2 = fminf(x2, jx2[jj]);
    float iy2 = fminf(y2, jy2[jj]);
    float iw = fmaxf(ix2 - ix1 + 1.0f, 0.0f);
    float ih = fmaxf(iy2 - iy1 + 1.0f, 0.0f);
    float inter = iw * ih;
    float uni = (ai + ja[jj]) - inter;   // uni > 0 always (areas >= 1)
    float t = inter + inter;             // exact (x2)
    bool gt = t > uni;
    bool amb = fabsf(t - uni) <= 1e-6f * uni;
    if (__ballot(amb) != 0ull) {         // ~never taken
      float iou = inter / uni;           // exact IEEE div, matches numpy
      if (amb) gt = iou > 0.5f;
    }
    bits |= ((u64)gt) << jj;
  }
  mtile[((size_t)gy * NT + gx) * 64 + l] = bits;
  mrow[(size_t)i * NT + gx] = bits;
  if (gx != gy) {
    u64 tb = 0;
#pragma unroll 8
    for (int c = 0; c < 64; ++c) {
      u64 wb = __ballot((bits >> c) & 1ull);
      tb = (l == c) ? wb : tb;
    }
    mtile[((size_t)gx * NT + gy) * 64 + l] = tb;
    mrow[(size_t)(gx * 64 + l) * NT + gy] = tb;
  }
}

// ---------------------------------------------------------------------------
// K5 (x NROUNDS): monotone parallel classification round.
// D = definitely-head bitmap, S = definitely-suppressed bitmap (128 u64 each).
// Sound rules (any stale view only delays, never corrupts):
//   suppressed: some earlier neighbor in D
//   head:       ALL earlier neighbors in S
// Correctness does NOT depend on convergence (k_fix is exact).
// ---------------------------------------------------------------------------
__global__ __launch_bounds__(256) void k_round(const u64* __restrict__ mtile,
                                               u64* __restrict__ D,
                                               u64* __restrict__ S) {
  __shared__ u64 Dl[NT], Sl[NT];
  __shared__ u64 bw[2][4];
  int gy = blockIdx.x;
  int t = threadIdx.x;
  if (t < NT) Dl[t] = D[t];
  else Sl[t - NT] = S[t - NT];
  __syncthreads();
  u64 classified = Dl[gy] | Sl[gy];
  if (classified == ~0ull) return;   // uniform
  int w = t >> 6, r = t & 63;
  bool unk = !((classified >> r) & 1ull);
  u64 anyD = 0, anyU = 0;
  if (unk) {
    int k0 = 32 * w, k1 = min(k0 + 32, gy + 1);
    for (int k = k0; k < k1; ++k) {
      u64 m = mtile[((size_t)gy * NT + k) * 64 + r];
      if (k == gy) m &= (1ull << r) - 1ull;   // strictly earlier within own tile
      anyD |= (m & Dl[k]);
      anyU |= (m & ~Sl[k]);
    }
  }
  u64 bD = __ballot(anyD != 0ull), bU = __ballot(anyU != 0ull);
  if (r == 0) { bw[0][w] = bD; bw[1][w] = bU; }
  __syncthreads();
  if (t == 0) {
    u64 rD = bw[0][0] | bw[0][1] | bw[0][2] | bw[0][3];
    u64 rU = bw[1][0] | bw[1][1] | bw[1][2] | bw[1][3];
    u64 unkb = ~classified;
    u64 newS = unkb & rD;
    u64 newD = unkb & ~rD & ~rU;
    if (newS) atomicOr(&S[gy], newS);
    if (newD) atomicOr(&D[gy], newD);
  }
}

// ---------------------------------------------------------------------------
// K6: exact serial cleanup, ONE wave. Processes unknown rows ascending.
// Invariant: when row j is tested, D contains ALL true heads < j. So
// (row_j & D & below) == 0 <=> j is a head. Exact for ANY round state.
// Rows fetched coalesced (1 KB) from mrow via 8-deep register ring.
// ---------------------------------------------------------------------------
__global__ __launch_bounds__(64, 1) void k_fix(const u64* __restrict__ mrow,
                                               u64* __restrict__ D,
                                               const u64* __restrict__ S) {
  __shared__ int ulist[N];
  int l = threadIdx.x;
  u64 D0 = D[2 * l], D1 = D[2 * l + 1];
  u64 S0 = S[2 * l], S1 = S[2 * l + 1];
  u64 u0 = ~(D0 | S0), u1 = ~(D1 | S1);
  int cnt = __popcll(u0) + __popcll(u1);
  int pre = cnt;
  for (int d = 1; d < 64; d <<= 1) {
    int v = __shfl_up(pre, d);
    if (l >= d) pre += v;
  }
  int M = __shfl(pre, 63);
  int off = pre - cnt;
  {
    u64 v = u0; int o = off;
    while (v) { int b = __builtin_ctzll(v); v &= v - 1; ulist[o++] = l * 128 + b; }
    v = u1;
    while (v) { int b = __builtin_ctzll(v); v &= v - 1; ulist[o++] = l * 128 + 64 + b; }
  }
  __syncthreads();
  if (M > 0) {
    ulong2 ring[8];
    int pj[8];
#pragma unroll
    for (int q = 0; q < 8; ++q) {
      int j = ulist[q < M ? q : M - 1];
      pj[q] = j;
      ring[q] = *(const ulong2*)&mrow[(size_t)j * NT + 2 * l];
    }
    for (int m = 0; m < M; ++m) {
      int slot = m & 7;
      int j = pj[slot];
      ulong2 rv = ring[slot];
      int jt = j >> 6;
      u64 bm = (1ull << (j & 63)) - 1ull;
      u64 m0 = (2 * l < jt) ? ~0ull : ((2 * l == jt) ? bm : 0ull);
      u64 m1 = (2 * l + 1 < jt) ? ~0ull : ((2 * l + 1 == jt) ? bm : 0ull);
      bool hit = ((rv.x & D0 & m0) | (rv.y & D1 & m1)) != 0ull;
      if (__ballot(hit) == 0ull) {          // no earlier head adjacent -> head
        if (l == (jt >> 1)) {
          if (jt & 1) D1 |= 1ull << (j & 63);
          else        D0 |= 1ull << (j & 63);
        }
      }
      int nm = m + 8;
      int j2 = ulist[nm < M ? nm : M - 1];
      pj[slot] = j2;
      ring[slot] = *(const ulong2*)&mrow[(size_t)j2 * NT + 2 * l];
    }
  }
  D[2 * l] = D0;
  D[2 * l + 1] = D1;
}

// ---------------------------------------------------------------------------
// K7: parallel cluster assignment + segment atomics. cluster[j] = first head
// adjacent to j (symmetry: row j == column j). Every j hits (itself if head).
// ---------------------------------------------------------------------------
__global__ __launch_bounds__(256) void k_cluster(const u64* __restrict__ mtile,
                                                 const u64* __restrict__ D,
                                                 const float* __restrict__ ss,
                                                 const float* __restrict__ by2s,
                                                 int* __restrict__ cluster,
                                                 int* __restrict__ cnt,
                                                 float* __restrict__ prob,
                                                 unsigned* __restrict__ y2m) {
  __shared__ u64 hlds[NT];
  __shared__ int red[4][64];
  int gy = blockIdx.x;
  if (threadIdx.x < NT) hlds[threadIdx.x] = D[threadIdx.x];
  __syncthreads();
  int w = threadIdx.x >> 6, r = threadIdx.x & 63;
  int best = 0x7fffffff;
  for (int kk = 0; kk < 32; ++kk) {
    int k = 32 * w + kk;
    u64 v = mtile[((size_t)gy * NT + k) * 64 + r] & hlds[k];
    if (v && best == 0x7fffffff) best = k * 64 + __builtin_ctzll(v);
  }
  red[w][r] = best;
  __syncthreads();
  if (w == 0) {
    int b = min(min(red[0][r], red[1][r]), min(red[2][r], red[3][r]));
    int j = gy * 64 + r;
    cluster[j] = b;
    atomicAdd(&cnt[b], 1);
    atomicAdd(&prob[b], ss[j]);
    atomicMax(&y2m[b], __float_as_uint(by2s[j]));
  }
}

// ---------------------------------------------------------------------------
// K8: first index achieving the cluster max y2
// ---------------------------------------------------------------------------
__global__ __launch_bounds__(256) void k_first(const int* __restrict__ cluster,
                                               const float* __restrict__ by2s,
                                               const unsigned* __restrict__ y2m,
                                               int* __restrict__ first) {
  int j = blockIdx.x * 256 + threadIdx.x;
  if (j >= N) return;
  int c = cluster[j];
  if (by2s[j] >= __uint_as_float(y2m[c])) atomicMin(&first[c], j);
}

// ---------------------------------------------------------------------------
// K9: outputs. out[j][0..4] then keep[j] appended (floats 0/1).
// ---------------------------------------------------------------------------
__global__ __launch_bounds__(256) void k_out(const int* __restrict__ cluster,
                                             const float* __restrict__ bx1s, const float* __restrict__ by1s,
                                             const float* __restrict__ bx2s, const float* __restrict__ by2s,
                                             const int* __restrict__ cnt,
                                             const float* __restrict__ prob,
                                             const int* __restrict__ first,
                                             const int* __restrict__ num_models,
                                             float* __restrict__ out) {
  int j = blockIdx.x * 256 + threadIdx.x;
  if (j >= N) return;
  int c = cluster[j];
  int nm = num_models[0];
  bool valid = (float)cnt[c] >= (float)nm / 3.0f;
  bool pick = (first[c] == j);
  bool keep = pick && valid;
  float o0 = 0.f, o1 = 0.f, o2 = 0.f, o3 = 0.f, o4 = 0.f;
  if (keep) {
    o0 = bx1s[j]; o1 = by1s[j]; o2 = bx2s[j]; o3 = by2s[j];
    o4 = prob[c] / (float)nm;
  }
  out[j * 5 + 0] = o0;
  out[j * 5 + 1] = o1;
  out[j * 5 + 2] = o2;
  out[j * 5 + 3] = o3;
  out[j * 5 + 4] = o4;
  out[N * 5 + j] = keep ? 1.0f : 0.0f;
}

// ---------------------------------------------------------------------------
extern "C" void kernel_launch(void* const* d_in, const int* in_sizes, int n_in,
                              void* d_out, int out_size, void* d_ws, size_t ws_size,
                              hipStream_t stream) {
  const float* boxes = (const float*)d_in[0];
  const float* scores = (const float*)d_in[1];
  const int* num_models = (const int*)d_in[2];
  float* out = (float*)d_out;

  char* p = (char*)d_ws;
  auto take = [&](size_t bytes) {
    char* r = p;
    p += (bytes + 255) & ~(size_t)255;
    return r;
  };
  u64* keys   = (u64*)take((size_t)N * 8);
  int* rank   = (int*)take((size_t)N * 4);
  float* bx1s = (float*)take((size_t)N * 4);
  float* by1s = (float*)take((size_t)N * 4);
  float* bx2s = (float*)take((size_t)N * 4);
  float* by2s = (float*)take((size_t)N * 4);
  float* ss   = (float*)take((size_t)N * 4);
  float* areas= (float*)take((size_t)N * 4);
  int* cluster= (int*)take((size_t)N * 4);
  int* cnt    = (int*)take((size_t)N * 4);
  float* prob = (float*)take((size_t)N * 4);
  unsigned* y2m = (unsigned*)take((size_t)N * 4);
  int* first  = (int*)take((size_t)N * 4);
  u64* D      = (u64*)take((size_t)NT * 8);           // head bitmap
  u64* S      = (u64*)take((size_t)NT * 8);           // suppressed bitmap
  u64* mtile  = (u64*)take((size_t)NT * NT * 64 * 8); // 8 MiB tiled adjacency
  u64* mrow   = (u64*)take((size_t)N * NT * 8);       // 8 MiB row-major adjacency

  k_init<<<N / 256, 256, 0, stream>>>(scores, keys, rank, cnt, prob, y2m, first, D, S);
  k_rank<<<dim3(N / 256, 8), 256, 0, stream>>>(keys, rank);
  k_scatter<<<N / 256, 256, 0, stream>>>(boxes, scores, rank, bx1s, by1s, bx2s, by2s, ss, areas);
  k_adj<<<NT * (NT + 1) / 2, 64, 0, stream>>>(bx1s, by1s, bx2s, by2s, areas, mtile, mrow);
  for (int r = 0; r < NROUNDS; ++r)
    k_round<<<NT, 256, 0, stream>>>(mtile, D, S);
  k_fix<<<1, 64, 0, stream>>>(mrow, D, S);
  k_cluster<<<N / 64, 256, 0, stream>>>(mtile, D, ss, by2s, cluster, cnt, prob, y2m);
  k_first<<<N / 256, 256, 0, stream>>>(cluster, by2s, y2m, first);
  k_out<<<N / 256, 256, 0, stream>>>(cluster, bx1s, by1s, bx2s, by2s, cnt, prob, first, num_models, out);
}

// Round 9
// 177.637 us; speedup vs baseline: 2.7444x; 1.0070x over previous
//
#include <hip/hip_runtime.h>
#include <cstdint>

#define N 8192
#define NT 128     // 64-col chunks per row (N/64)
#define NROUNDS 8  // parallel classification rounds (correctness-independent)
typedef unsigned long long u64;
typedef unsigned int u32;

// ---------------------------------------------------------------------------
// K1: sort keys (descending score, stable ascending index) + init aux + D,S=0
// ---------------------------------------------------------------------------
__global__ __launch_bounds__(256) void k_init(const float* __restrict__ scores,
                                              u64* __restrict__ keys,
                                              int* __restrict__ rank,
                                              int* __restrict__ cnt,
                                              float* __restrict__ prob,
                                              unsigned* __restrict__ y2m,
                                              int* __restrict__ first,
                                              u64* __restrict__ D,
                                              u64* __restrict__ S) {
  int i = blockIdx.x * 256 + threadIdx.x;
  if (i >= N) return;
  float sc = scores[i];
  keys[i] = ((u64)__float_as_uint(sc) << 32) | (unsigned)(0xFFFFFFFFu - (unsigned)i);
  rank[i] = 0;
  cnt[i] = 0;
  prob[i] = 0.0f;
  y2m[i] = 0u;
  first[i] = N;
  if (i < NT) { D[i] = 0ull; S[i] = 0ull; }
}

// ---------------------------------------------------------------------------
// K2: rank by counting (rank[i] = #{j : key[j] > key[i]}) -> stable descending
// ---------------------------------------------------------------------------
__global__ __launch_bounds__(256) void k_rank(const u64* __restrict__ keys,
                                              int* __restrict__ rank) {
  __shared__ u64 tile[1024];
  int e = blockIdx.x * 256 + threadIdx.x;
  int j0 = blockIdx.y * 1024;
  for (int t = threadIdx.x; t < 1024; t += 256) tile[t] = keys[j0 + t];
  __syncthreads();
  u64 ke = keys[e];
  int c = 0;
#pragma unroll 8
  for (int k = 0; k < 1024; ++k) c += (tile[k] > ke) ? 1 : 0;
  atomicAdd(&rank[e], c);
}

// ---------------------------------------------------------------------------
// K3: scatter into sorted SoA (clipped coords, score, area)
// ---------------------------------------------------------------------------
__global__ __launch_bounds__(256) void k_scatter(const float* __restrict__ boxes,
                                                 const float* __restrict__ scores,
                                                 const int* __restrict__ rank,
                                                 float* __restrict__ bx1s, float* __restrict__ by1s,
                                                 float* __restrict__ bx2s, float* __restrict__ by2s,
                                                 float* __restrict__ ss, float* __restrict__ areas) {
#pragma clang fp contract(off)
  int i = blockIdx.x * 256 + threadIdx.x;
  if (i >= N) return;
  int r = rank[i];
  float x1 = fminf(fmaxf(boxes[i * 4 + 0], 0.0f), 1920.0f);
  float y1 = fminf(fmaxf(boxes[i * 4 + 1], 0.0f), 1080.0f);
  float x2 = fminf(fmaxf(boxes[i * 4 + 2], 0.0f), 1920.0f);
  float y2 = fminf(fmaxf(boxes[i * 4 + 3], 0.0f), 1080.0f);
  bx1s[r] = x1; by1s[r] = y1; bx2s[r] = x2; by2s[r] = y2;
  ss[r] = scores[i];
  areas[r] = (x2 - x1 + 1.0f) * (y2 - y1 + 1.0f);
}

// ---------------------------------------------------------------------------
// K4: adjacency, SYMMETRIC lower-triangle blocks + ballot transpose.
// Band trick (R8, verified absmax 0.0): iou>0.5 <=> 2*inter>uni whenever
// |2*inter-uni| > 1e-6*uni (RN div error <= 3e-8 rel << band margin); only
// in-band lanes (~1e2 of 33.8M) take the exact IEEE divide, ballot-guarded.
// fp contract OFF everywhere; matrix float-exact symmetric.
// ---------------------------------------------------------------------------
__global__ __launch_bounds__(64) void k_adj(const float* __restrict__ bx1s, const float* __restrict__ by1s,
                                            const float* __restrict__ bx2s, const float* __restrict__ by2s,
                                            const float* __restrict__ areas,
                                            u64* __restrict__ mtile,
                                            u64* __restrict__ mrow) {
#pragma clang fp contract(off)
  __shared__ float jx1[64], jy1[64], jx2[64], jy2[64], ja[64];
  int p = blockIdx.x;
  int gy = (int)((sqrtf(8.0f * (float)p + 1.0f) - 1.0f) * 0.5f);
  while ((gy + 1) * (gy + 2) / 2 <= p) ++gy;
  while (gy * (gy + 1) / 2 > p) --gy;
  int gx = p - gy * (gy + 1) / 2;

  int l = threadIdx.x;
  int j = gx * 64 + l;
  jx1[l] = bx1s[j]; jy1[l] = by1s[j]; jx2[l] = bx2s[j]; jy2[l] = by2s[j]; ja[l] = areas[j];
  __syncthreads();
  int i = gy * 64 + l;
  float x1 = bx1s[i], y1 = by1s[i], x2 = bx2s[i], y2 = by2s[i], ai = areas[i];
  u64 bits = 0;
#pragma unroll 4
  for (int jj = 0; jj < 64; ++jj) {
    float ix1 = fmaxf(x1, jx1[jj]);
    float iy1 = fmaxf(y1, jy1[jj]);
    float ix2 = fminf(x2, jx2[jj]);
    float iy2 = fminf(y2, jy2[jj]);
    float iw = fmaxf(ix2 - ix1 + 1.0f, 0.0f);
    float ih = fmaxf(iy2 - iy1 + 1.0f, 0.0f);
    float inter = iw * ih;
    float uni = (ai + ja[jj]) - inter;   // uni > 0 always (areas >= 1)
    float t = inter + inter;             // exact (x2)
    bool gt = t > uni;
    bool amb = fabsf(t - uni) <= 1e-6f * uni;
    if (__ballot(amb) != 0ull) {         // ~never taken
      float iou = inter / uni;           // exact IEEE div, matches numpy
      if (amb) gt = iou > 0.5f;
    }
    bits |= ((u64)gt) << jj;
  }
  mtile[((size_t)gy * NT + gx) * 64 + l] = bits;
  mrow[(size_t)i * NT + gx] = bits;
  if (gx != gy) {
    u64 tb = 0;
#pragma unroll 8
    for (int c = 0; c < 64; ++c) {
      u64 wb = __ballot((bits >> c) & 1ull);
      tb = (l == c) ? wb : tb;
    }
    mtile[((size_t)gx * NT + gy) * 64 + l] = tb;
    mrow[(size_t)(gx * 64 + l) * NT + gy] = tb;
  }
}

// ---------------------------------------------------------------------------
// K5 (x NROUNDS): monotone parallel classification round.
// D = definitely-head bitmap, S = definitely-suppressed bitmap (128 u64 each).
// Sound rules (any stale view only delays, never corrupts):
//   suppressed: some earlier neighbor in D
//   head:       ALL earlier neighbors in S
// Correctness does NOT depend on convergence (k_fix is exact). R8 showed
// k_fix cost is sharply M-sensitive: 4 rounds -> k_fix 105us; 8 rounds keeps
// M small (R7: k_fix < 42us) for +10us of launches.
// ---------------------------------------------------------------------------
__global__ __launch_bounds__(256) void k_round(const u64* __restrict__ mtile,
                                               u64* __restrict__ D,
                                               u64* __restrict__ S) {
  __shared__ u64 Dl[NT], Sl[NT];
  __shared__ u64 bw[2][4];
  int gy = blockIdx.x;
  int t = threadIdx.x;
  if (t < NT) Dl[t] = D[t];
  else Sl[t - NT] = S[t - NT];
  __syncthreads();
  u64 classified = Dl[gy] | Sl[gy];
  if (classified == ~0ull) return;   // uniform
  int w = t >> 6, r = t & 63;
  bool unk = !((classified >> r) & 1ull);
  u64 anyD = 0, anyU = 0;
  if (unk) {
    int k0 = 32 * w, k1 = min(k0 + 32, gy + 1);
    for (int k = k0; k < k1; ++k) {
      u64 m = mtile[((size_t)gy * NT + k) * 64 + r];
      if (k == gy) m &= (1ull << r) - 1ull;   // strictly earlier within own tile
      anyD |= (m & Dl[k]);
      anyU |= (m & ~Sl[k]);
    }
  }
  u64 bD = __ballot(anyD != 0ull), bU = __ballot(anyU != 0ull);
  if (r == 0) { bw[0][w] = bD; bw[1][w] = bU; }
  __syncthreads();
  if (t == 0) {
    u64 rD = bw[0][0] | bw[0][1] | bw[0][2] | bw[0][3];
    u64 rU = bw[1][0] | bw[1][1] | bw[1][2] | bw[1][3];
    u64 unkb = ~classified;
    u64 newS = unkb & rD;
    u64 newD = unkb & ~rD & ~rU;
    if (newS) atomicOr(&S[gy], newS);
    if (newD) atomicOr(&D[gy], newD);
  }
}

// ---------------------------------------------------------------------------
// K6: exact serial cleanup, ONE wave, BRANCHLESS inner loop (R8: 105us at
// ~60cy/unknown, two branches + masked-update on the serial chain; now the
// chain is hit-AND/OR -> v_cmp ballot -> uniform head flag -> cndmask OR,
// ~25-30cy). Invariant: when row j is tested, D contains ALL true heads < j,
// so (row_j & D & below) == 0 <=> j is a head. Exact for ANY round state.
// Rows fetched coalesced (1 KB) from mrow via 8-deep register ring.
// ---------------------------------------------------------------------------
__global__ __launch_bounds__(64, 1) void k_fix(const u64* __restrict__ mrow,
                                               u64* __restrict__ D,
                                               const u64* __restrict__ S) {
  __shared__ int ulist[N];
  int l = threadIdx.x;
  u64 D0 = D[2 * l], D1 = D[2 * l + 1];
  u64 S0 = S[2 * l], S1 = S[2 * l + 1];
  u64 u0 = ~(D0 | S0), u1 = ~(D1 | S1);
  int cnt = __popcll(u0) + __popcll(u1);
  int pre = cnt;
  for (int d = 1; d < 64; d <<= 1) {
    int v = __shfl_up(pre, d);
    if (l >= d) pre += v;
  }
  int M = __shfl(pre, 63);
  int off = pre - cnt;
  {
    u64 v = u0; int o = off;
    while (v) { int b = __builtin_ctzll(v); v &= v - 1; ulist[o++] = l * 128 + b; }
    v = u1;
    while (v) { int b = __builtin_ctzll(v); v &= v - 1; ulist[o++] = l * 128 + 64 + b; }
  }
  __syncthreads();
  if (M > 0) {
    ulong2 ring[8];
    int pj[8];
#pragma unroll
    for (int q = 0; q < 8; ++q) {
      int j = ulist[q < M ? q : M - 1];
      pj[q] = j;
      ring[q] = *(const ulong2*)&mrow[(size_t)j * NT + 2 * l];
    }
    for (int m = 0; m < M; ++m) {
      int slot = m & 7;
      int j = pj[slot];
      ulong2 rv = ring[slot];
      int jt = j >> 6;                       // uniform
      u64 bm = (1ull << (j & 63)) - 1ull;
      u64 m0 = (2 * l < jt) ? ~0ull : ((2 * l == jt) ? bm : 0ull);
      u64 m1 = (2 * l + 1 < jt) ? ~0ull : ((2 * l + 1 == jt) ? bm : 0ull);
      bool hit = ((rv.x & D0 & m0) | (rv.y & D1 & m1)) != 0ull;
      bool head = (__ballot(hit) == 0ull);   // uniform
      u64 bset = 1ull << (j & 63);
      D0 |= (head && (2 * l == jt)) ? bset : 0ull;       // branchless update
      D1 |= (head && (2 * l + 1 == jt)) ? bset : 0ull;
      int nm = m + 8;
      int j2 = ulist[nm < M ? nm : M - 1];
      pj[slot] = j2;
      ring[slot] = *(const ulong2*)&mrow[(size_t)j2 * NT + 2 * l];
    }
  }
  D[2 * l] = D0;
  D[2 * l + 1] = D1;
}

// ---------------------------------------------------------------------------
// K7: parallel cluster assignment + segment atomics. cluster[j] = first head
// adjacent to j (symmetry: row j == column j). Every j hits (itself if head).
// ---------------------------------------------------------------------------
__global__ __launch_bounds__(256) void k_cluster(const u64* __restrict__ mtile,
                                                 const u64* __restrict__ D,
                                                 const float* __restrict__ ss,
                                                 const float* __restrict__ by2s,
                                                 int* __restrict__ cluster,
                                                 int* __restrict__ cnt,
                                                 float* __restrict__ prob,
                                                 unsigned* __restrict__ y2m) {
  __shared__ u64 hlds[NT];
  __shared__ int red[4][64];
  int gy = blockIdx.x;
  if (threadIdx.x < NT) hlds[threadIdx.x] = D[threadIdx.x];
  __syncthreads();
  int w = threadIdx.x >> 6, r = threadIdx.x & 63;
  int best = 0x7fffffff;
  for (int kk = 0; kk < 32; ++kk) {
    int k = 32 * w + kk;
    u64 v = mtile[((size_t)gy * NT + k) * 64 + r] & hlds[k];
    if (v && best == 0x7fffffff) best = k * 64 + __builtin_ctzll(v);
  }
  red[w][r] = best;
  __syncthreads();
  if (w == 0) {
    int b = min(min(red[0][r], red[1][r]), min(red[2][r], red[3][r]));
    int j = gy * 64 + r;
    cluster[j] = b;
    atomicAdd(&cnt[b], 1);
    atomicAdd(&prob[b], ss[j]);
    atomicMax(&y2m[b], __float_as_uint(by2s[j]));
  }
}

// ---------------------------------------------------------------------------
// K8: first index achieving the cluster max y2
// ---------------------------------------------------------------------------
__global__ __launch_bounds__(256) void k_first(const int* __restrict__ cluster,
                                               const float* __restrict__ by2s,
                                               const unsigned* __restrict__ y2m,
                                               int* __restrict__ first) {
  int j = blockIdx.x * 256 + threadIdx.x;
  if (j >= N) return;
  int c = cluster[j];
  if (by2s[j] >= __uint_as_float(y2m[c])) atomicMin(&first[c], j);
}

// ---------------------------------------------------------------------------
// K9: outputs. out[j][0..4] then keep[j] appended (floats 0/1).
// ---------------------------------------------------------------------------
__global__ __launch_bounds__(256) void k_out(const int* __restrict__ cluster,
                                             const float* __restrict__ bx1s, const float* __restrict__ by1s,
                                             const float* __restrict__ bx2s, const float* __restrict__ by2s,
                                             const int* __restrict__ cnt,
                                             const float* __restrict__ prob,
                                             const int* __restrict__ first,
                                             const int* __restrict__ num_models,
                                             float* __restrict__ out) {
  int j = blockIdx.x * 256 + threadIdx.x;
  if (j >= N) return;
  int c = cluster[j];
  int nm = num_models[0];
  bool valid = (float)cnt[c] >= (float)nm / 3.0f;
  bool pick = (first[c] == j);
  bool keep = pick && valid;
  float o0 = 0.f, o1 = 0.f, o2 = 0.f, o3 = 0.f, o4 = 0.f;
  if (keep) {
    o0 = bx1s[j]; o1 = by1s[j]; o2 = bx2s[j]; o3 = by2s[j];
    o4 = prob[c] / (float)nm;
  }
  out[j * 5 + 0] = o0;
  out[j * 5 + 1] = o1;
  out[j * 5 + 2] = o2;
  out[j * 5 + 3] = o3;
  out[j * 5 + 4] = o4;
  out[N * 5 + j] = keep ? 1.0f : 0.0f;
}

// ---------------------------------------------------------------------------
extern "C" void kernel_launch(void* const* d_in, const int* in_sizes, int n_in,
                              void* d_out, int out_size, void* d_ws, size_t ws_size,
                              hipStream_t stream) {
  const float* boxes = (const float*)d_in[0];
  const float* scores = (const float*)d_in[1];
  const int* num_models = (const int*)d_in[2];
  float* out = (float*)d_out;

  char* p = (char*)d_ws;
  auto take = [&](size_t bytes) {
    char* r = p;
    p += (bytes + 255) & ~(size_t)255;
    return r;
  };
  u64* keys   = (u64*)take((size_t)N * 8);
  int* rank   = (int*)take((size_t)N * 4);
  float* bx1s = (float*)take((size_t)N * 4);
  float* by1s = (float*)take((size_t)N * 4);
  float* bx2s = (float*)take((size_t)N * 4);
  float* by2s = (float*)take((size_t)N * 4);
  float* ss   = (float*)take((size_t)N * 4);
  float* areas= (float*)take((size_t)N * 4);
  int* cluster= (int*)take((size_t)N * 4);
  int* cnt    = (int*)take((size_t)N * 4);
  float* prob = (float*)take((size_t)N * 4);
  unsigned* y2m = (unsigned*)take((size_t)N * 4);
  int* first  = (int*)take((size_t)N * 4);
  u64* D      = (u64*)take((size_t)NT * 8);           // head bitmap
  u64* S      = (u64*)take((size_t)NT * 8);           // suppressed bitmap
  u64* mtile  = (u64*)take((size_t)NT * NT * 64 * 8); // 8 MiB tiled adjacency
  u64* mrow   = (u64*)take((size_t)N * NT * 8);       // 8 MiB row-major adjacency

  k_init<<<N / 256, 256, 0, stream>>>(scores, keys, rank, cnt, prob, y2m, first, D, S);
  k_rank<<<dim3(N / 256, 8), 256, 0, stream>>>(keys, rank);
  k_scatter<<<N / 256, 256, 0, stream>>>(boxes, scores, rank, bx1s, by1s, bx2s, by2s, ss, areas);
  k_adj<<<NT * (NT + 1) / 2, 64, 0, stream>>>(bx1s, by1s, bx2s, by2s, areas, mtile, mrow);
  for (int r = 0; r < NROUNDS; ++r)
    k_round<<<NT, 256, 0, stream>>>(mtile, D, S);
  k_fix<<<1, 64, 0, stream>>>(mrow, D, S);
  k_cluster<<<N / 64, 256, 0, stream>>>(mtile, D, ss, by2s, cluster, cnt, prob, y2m);
  k_first<<<N / 256, 256, 0, stream>>>(cluster, by2s, y2m, first);
  k_out<<<N / 256, 256, 0, stream>>>(cluster, bx1s, by1s, bx2s, by2s, cnt, prob, first, num_models, out);
}